// Round 10
// baseline (486.083 us; speedup 1.0000x reference)
//
#include <hip/hip_runtime.h>
#include <stdint.h>

#define HW     65160      // H*W = 181*360
#define W_LON  360
#define H_LAT  181
#define T_OUT  181
#define NB     2
#define NC     128
#define NF     128
#define NK     3
#define NSEG   (NK * T_OUT)   // 543 segments, id = k*181 + t
#define XROWS  65280          // padded hw rows for xt (255*256)
// sparse LDS: per row r(=dl) two parity copies of the 720-elem duplicated bf16 row,
// stored as uint words: A[j] = elems(2j,2j+1), B[j] = elems(2j+1,2j+2), j in [0,360)
#define RW     720            // words per row (A 360 + B 360)
#define LDSW   (7 * RW + 16)  // + pad so discarded lanes (tid 180..191) stay in-bounds

typedef __attribute__((ext_vector_type(8))) short bf16x8;
typedef __attribute__((ext_vector_type(4))) float f32x4;
typedef __attribute__((ext_vector_type(2))) float f32x2;

#define AS1(p) ((const __attribute__((address_space(1))) void*)(p))
#define AS3(p) ((__attribute__((address_space(3))) void*)(p))

static __device__ inline ushort f2bf(float v) {
    unsigned u = __float_as_uint(v);
    unsigned r = (u + 0x7FFFu + ((u >> 16) & 1u)) >> 16;
    return (ushort)r;
}
static __device__ inline float bf2f(ushort h) {
    return __uint_as_float(((unsigned)h) << 16);
}
static __device__ inline f32x2 fma2(f32x2 a, f32x2 b, f32x2 c) {
#if __has_builtin(__builtin_elementwise_fma)
    return __builtin_elementwise_fma(a, b, c);
#else
    f32x2 r; r[0] = fmaf(a[0], b[0], c[0]); r[1] = fmaf(a[1], b[1], c[1]); return r;
#endif
}

// ---------------- prep kernels ----------------

// weight (F,C,K) fp32 -> wt_h/wt_l [k][f][c] bf16 (c contiguous)
__global__ void k_transpose_w(const float* __restrict__ w,
                              ushort* __restrict__ wt_h, ushort* __restrict__ wt_l) {
    int i = blockIdx.x * 256 + threadIdx.x;
    if (i >= NK * NF * NC) return;
    int k = i / (NF * NC);
    int f = (i / NC) % NF;
    int c = i % NC;
    float v = w[(f * NC + c) * NK + k];
    ushort h = f2bf(v);
    ushort l = f2bf(v - bf2f(h));
    wt_h[i] = h;
    wt_l[i] = l;
}

// segment bounds via binary search: entry order is t-major then k, so
// key(n) = (seg%181)*3 + seg/181 is monotone non-decreasing in n.
__global__ void k_bounds(const int* __restrict__ seg, int* __restrict__ row_start,
                         int* __restrict__ row_end, int nnz) {
    int s = blockIdx.x * 256 + threadIdx.x;
    if (s >= NSEG) return;
    int t = s % T_OUT, k = s / T_OUT;
    int key = t * NK + k;
    int lo = 0, hi = nnz;
    while (lo < hi) {                      // lower_bound
        int mid = (lo + hi) >> 1;
        int sm = seg[mid];
        int km = (sm % T_OUT) * NK + sm / T_OUT;
        if (km < key) lo = mid + 1; else hi = mid;
    }
    row_start[s] = lo;
    int lo2 = lo; hi = nnz;
    while (lo2 < hi) {                     // upper_bound
        int mid = (lo2 + hi) >> 1;
        int sm = seg[mid];
        int km = (sm % T_OUT) * NK + sm / T_OUT;
        if (km <= key) lo2 = mid + 1; else hi = mid;
    }
    row_end[s] = lo2;
}

// pack each entry as (lds WORD offset, val*qw[lat]):
//   ofs = dl*RW + (lon&1)*360 + (lon>>1)   (parity selects copy A or B)
// gather lane q reads word ofs+q = bf16 elems (lon+2q, lon+2q+1) of row dl.
__global__ void k_pack(const int* __restrict__ seg, const int* __restrict__ lat,
                       const int* __restrict__ lon, const float* __restrict__ vals,
                       const float* __restrict__ qw,
                       uint2* __restrict__ packed, int nnz) {
    int n = blockIdx.x * 256 + threadIdx.x;
    if (n >= nnz) return;
    int s = seg[n];
    int k = s / T_OUT;
    int t = s - k * T_OUT;
    int la = lat[n];
    int dl = la - (t - 3);
    dl = max(0, min(6, dl));                  // mathematically always in [0,6]
    int lo = lon[n];
    unsigned ofs = (unsigned)(dl * RW + (lo & 1) * 360 + (lo >> 1));
    float v = vals[n] * qw[la];               // fold quadrature weight into psi
    packed[n] = make_uint2(ofs, __float_as_uint(v));
}

// x [b][c][hw] fp32 -> xt_h [b][hw][c] bf16 (c contiguous). hi-part only.
__global__ __launch_bounds__(256) void k_split(const float* __restrict__ x,
                                               ushort* __restrict__ xt_h) {
    int b = blockIdx.y;
    int hw0 = blockIdx.x * 64;
    __shared__ float t[128][65];
    int tid = threadIdx.x;
    int quad = tid & 15;              // 16 quads = 64 floats per row
    int r0 = tid >> 4;                // 16 rows per iteration
    bool full = (hw0 + 64 <= HW);
#pragma unroll
    for (int rr = 0; rr < 8; ++rr) {
        int c = rr * 16 + r0;
        const float* src = x + ((size_t)b * NC + c) * HW + hw0 + quad * 4;
        float4 v;
        if (full) {
            v = *(const float4*)src;
        } else {
            int base = hw0 + quad * 4;
            v.x = (base + 0 < HW) ? src[0] : 0.f;
            v.y = (base + 1 < HW) ? src[1] : 0.f;
            v.z = (base + 2 < HW) ? src[2] : 0.f;
            v.w = (base + 3 < HW) ? src[3] : 0.f;
        }
        *(float4*)&t[c][quad * 4] = v;
    }
    __syncthreads();
    int hwl = tid >> 2;               // 64 hw per block
    int c0 = (tid & 3) * 32;          // 4 c-chunks of 32
    int hw = hw0 + hwl;
    if (hw < HW) {
        ushort hb[32];
#pragma unroll
        for (int cc = 0; cc < 32; ++cc)
            hb[cc] = f2bf(t[c0 + cc][hwl]);
        size_t off = ((size_t)b * XROWS + hw) * NC + c0;
#pragma unroll
        for (int j = 0; j < 4; ++j)
            *(int4*)(xt_h + off + j * 8) = *(int4*)(hb + j * 8);
    }
}

// ---------------- stage 1: bf16 MFMA GEMM ----------------
// z[b][k][zbase+fl][hw] = sum_c (Wh+Wl)[f,c,k]*Xh[b,c,hw], stored BF16.
template<int MT>
__global__ __launch_bounds__(256)
void k_gemm2(const ushort* __restrict__ xt_h,
             const ushort* __restrict__ wt_h, const ushort* __restrict__ wt_l,
             ushort* __restrict__ z, int cf0, int zcf, int zbase) {
    constexpr int MTILES = MT / 16;
    int tid = threadIdx.x;
    int bk = blockIdx.y;
    int b = bk / NK, k = bk % NK;
    int hwb = blockIdx.x * 256;

    __shared__ ushort smem[2 * MT * 32 + 256 * 32];
    ushort* Ah = smem;                  // MT rows x 32 c
    ushort* Al = smem + MT * 32;
    ushort* Bh = smem + 2 * MT * 32;    // 256 rows x 32 c

    int lane = tid & 63;
    int wv = tid >> 6;
    int m = lane & 15, q0 = lane >> 4;
    int eoff = (m * 4 + (q0 ^ ((m >> 1) & 3))) * 8;   // ushort offset of this lane's chunk

    f32x4 acc[MTILES][4];
#pragma unroll
    for (int i = 0; i < MTILES; ++i)
#pragma unroll
        for (int j = 0; j < 4; ++j) acc[i][j] = (f32x4){0.f, 0.f, 0.f, 0.f};

    for (int c0 = 0; c0 < NC; c0 += 32) {
        if (tid < MT * 4) {
            int f = tid >> 2, s = tid & 3;
            int q = s ^ ((f >> 1) & 3);
            size_t gi = ((size_t)(k * NF + cf0 + f)) * NC + c0 + q * 8;
            int i0 = tid & ~63;
            __builtin_amdgcn_global_load_lds(AS1(wt_h + gi), AS3(Ah + i0 * 8), 16, 0, 0);
            __builtin_amdgcn_global_load_lds(AS1(wt_l + gi), AS3(Al + i0 * 8), 16, 0, 0);
        }
#pragma unroll
        for (int it = 0; it < 4; ++it) {
            int i = it * 256 + tid;
            int r = i >> 2, s = i & 3;
            int q = s ^ ((r >> 1) & 3);
            size_t gi = ((size_t)b * XROWS + hwb + r) * NC + c0 + q * 8;
            int i0 = i & ~63;
            __builtin_amdgcn_global_load_lds(AS1(xt_h + gi), AS3(Bh + i0 * 8), 16, 0, 0);
        }
        __syncthreads();

        bf16x8 ah[MTILES], al[MTILES], bh[4];
#pragma unroll
        for (int mt = 0; mt < MTILES; ++mt) {
            ah[mt] = *(const bf16x8*)(Ah + mt * 512 + eoff);
            al[mt] = *(const bf16x8*)(Al + mt * 512 + eoff);
        }
#pragma unroll
        for (int nt = 0; nt < 4; ++nt)
            bh[nt] = *(const bf16x8*)(Bh + wv * 2048 + nt * 512 + eoff);
#pragma unroll
        for (int mt = 0; mt < MTILES; ++mt)
#pragma unroll
            for (int nt = 0; nt < 4; ++nt) {
                acc[mt][nt] = __builtin_amdgcn_mfma_f32_16x16x32_bf16(ah[mt], bh[nt], acc[mt][nt], 0, 0, 0);
                acc[mt][nt] = __builtin_amdgcn_mfma_f32_16x16x32_bf16(al[mt], bh[nt], acc[mt][nt], 0, 0, 0);
            }
        __syncthreads();
    }

#pragma unroll
    for (int mt = 0; mt < MTILES; ++mt)
#pragma unroll
        for (int nt = 0; nt < 4; ++nt) {
            int n = hwb + wv * 64 + nt * 16 + m;
            if (n < HW) {
                f32x4 a = acc[mt][nt];
#pragma unroll
                for (int r = 0; r < 4; ++r) {
                    int fl = mt * 16 + q0 * 4 + r;
                    z[((size_t)(b * NK + k) * zcf + zbase + fl) * HW + n] = f2bf(a[r]);
                }
            }
        }
}

// ---------------- stage 2: gather/accumulate + bias ----------------
// v10 = v9 + DEEP staging pipeline: k0 and k1 loads issued in the prologue,
// k2 issued right after k0's LDS write. Every plane's data is resident in
// registers long before its write barrier -> no phase waits on L2/HBM, which
// was the exposed latency for short (equator) gather rows. Static register
// sets aA/aB/aC (no runtime-indexed arrays -> stays in VGPRs). Gather loop
// byte-identical to R8/R9 (codegen-fragility lesson).
__global__ void __launch_bounds__(192)
k_sparse(const ushort* __restrict__ z, const uint2* __restrict__ packed,
         const int* __restrict__ row_start, const int* __restrict__ row_end,
         const float* __restrict__ bias,
         float* __restrict__ out, int cf0, int CF) {
    int y  = blockIdx.y;
    int t  = (y & 1) ? (T_OUT - 1 - (y >> 1)) : (y >> 1);   // pole-first order
    int ch = blockIdx.x;                 // [0, 2*CF)
    int b  = ch / CF;
    int fl = ch % CF;
    int fg = cf0 + fl;
    int tid = threadIdx.x;               // 192; lanes 180..191 discarded
    __shared__ unsigned lds32[LDSW];     // 20224 B

    int lat0 = t - 3;
    f32x2 acc = {0.f, 0.f};

    // fixed per-thread staging slots (7 rows x 45 uint4-chunks = 315)
    int c0s = tid,        r0s = c0s / 45, cj0 = (c0s - r0s * 45) * 4, la0 = lat0 + r0s;
    int c1s = tid + 192;
    int r1s = c1s / 45,   cj1 = (c1s - r1s * 45) * 4, la1 = lat0 + r1s;
    bool v0 = (la0 >= 0 && la0 < H_LAT);
    bool v1 = (c1s < 315) && (la1 >= 0 && la1 < H_LAT);
    int nw0 = (cj0 + 4 < 180) ? cj0 + 4 : 0;
    int nw1 = (cj1 + 4 < 180) ? cj1 + 4 : 0;
    const size_t zpstride = (size_t)CF * HW;
    const ushort* zb = &z[(size_t)(b * NK) * zpstride + (size_t)fl * HW];

    uint4 aA0 = (uint4){0,0,0,0}, aA1 = (uint4){0,0,0,0};
    uint4 aB0 = (uint4){0,0,0,0}, aB1 = (uint4){0,0,0,0};
    uint4 aC0 = (uint4){0,0,0,0}, aC1 = (uint4){0,0,0,0};
    unsigned nA0 = 0, nA1 = 0, nB0 = 0, nB1 = 0, nC0 = 0, nC1 = 0;

#define STG_LOAD(A0, A1, N0, N1, ZP) do { \
        const unsigned* g0_ = (const unsigned*)((ZP) + la0 * W_LON); \
        const unsigned* g1_ = (const unsigned*)((ZP) + la1 * W_LON); \
        if (v0) { A0 = *(const uint4*)(g0_ + cj0); N0 = g0_[nw0]; } \
        if (v1) { A1 = *(const uint4*)(g1_ + cj1); N1 = g1_[nw1]; } \
    } while (0)

#define STG_WRITE(A0, A1, N0, N1) do { \
        if (v0) { \
            uint4 bw_; \
            bw_.x = (A0.x >> 16) | (A0.y << 16); \
            bw_.y = (A0.y >> 16) | (A0.z << 16); \
            bw_.z = (A0.z >> 16) | (A0.w << 16); \
            bw_.w = (A0.w >> 16) | (N0 << 16); \
            unsigned* base_ = &lds32[r0s * RW + cj0]; \
            *(uint4*)(base_)       = A0; \
            *(uint4*)(base_ + 180) = A0; \
            *(uint4*)(base_ + 360) = bw_; \
            *(uint4*)(base_ + 540) = bw_; \
        } \
        if (v1) { \
            uint4 bw_; \
            bw_.x = (A1.x >> 16) | (A1.y << 16); \
            bw_.y = (A1.y >> 16) | (A1.z << 16); \
            bw_.z = (A1.z >> 16) | (A1.w << 16); \
            bw_.w = (A1.w >> 16) | (N1 << 16); \
            unsigned* base_ = &lds32[r1s * RW + cj1]; \
            *(uint4*)(base_)       = A1; \
            *(uint4*)(base_ + 180) = A1; \
            *(uint4*)(base_ + 360) = bw_; \
            *(uint4*)(base_ + 540) = bw_; \
        } \
    } while (0)

#define GATHER(KK) do { \
        int s_ = (KK) * T_OUT + t; \
        int ns_ = row_start[s_], ne_ = row_end[s_]; \
        _Pragma("unroll 4") \
        for (int n = ns_; n < ne_; ++n) { \
            uint2 e = packed[n]; \
            float v = __uint_as_float(e.y); \
            unsigned u = lds32[(int)e.x + tid]; \
            f32x2 xv; \
            xv[0] = __uint_as_float(u << 16); \
            xv[1] = __uint_as_float(u & 0xFFFF0000u); \
            f32x2 vv = {v, v}; \
            acc = fma2(vv, xv, acc); \
        } \
    } while (0)

    // prologue: issue k0 and k1 plane loads
    STG_LOAD(aA0, aA1, nA0, nA1, zb);
    STG_LOAD(aB0, aB1, nB0, nB1, zb + zpstride);

    // k = 0
    __syncthreads();
    STG_WRITE(aA0, aA1, nA0, nA1);
    __syncthreads();
    STG_LOAD(aC0, aC1, nC0, nC1, zb + 2 * zpstride);   // k2 in flight during k0 gather
    GATHER(0);

    // k = 1
    __syncthreads();
    STG_WRITE(aB0, aB1, nB0, nB1);
    __syncthreads();
    GATHER(1);

    // k = 2
    __syncthreads();
    STG_WRITE(aC0, aC1, nC0, nC1);
    __syncthreads();
    GATHER(2);

#undef STG_LOAD
#undef STG_WRITE
#undef GATHER

    if (tid < 180) {
        float bs = bias[fg];
        size_t ob = (size_t)((b * NF + fg) * T_OUT + t) * W_LON;
        float2 o = make_float2(acc[0] + bs, acc[1] + bs);
        *(float2*)&out[ob + 2 * tid] = o;
    }
}

// ---------------- launch ----------------
extern "C" void kernel_launch(void* const* d_in, const int* in_sizes, int n_in,
                              void* d_out, int out_size, void* d_ws, size_t ws_size,
                              hipStream_t stream) {
    const float* x    = (const float*)d_in[0];
    const float* qw   = (const float*)d_in[1];
    const float* vals = (const float*)d_in[2];
    const float* w    = (const float*)d_in[3];
    const float* bias = (const float*)d_in[4];
    const int*   seg  = (const int*)d_in[5];
    const int*   lat  = (const int*)d_in[6];
    const int*   lon  = (const int*)d_in[7];
    int nnz = in_sizes[2];
    float* out = (float*)d_out;

    char* wsb = (char*)d_ws;
    ushort* wt_h     = (ushort*)wsb;                        // 98304 B
    ushort* wt_l     = (ushort*)(wsb + 98304);              // 98304 B
    int*    row_start= (int*)(wsb + 196608);                // 2304 B
    int*    row_end  = (int*)(wsb + 198912);                // 2304 B
    uint2*  packed   = (uint2*)(wsb + 201216);              // nnz*8 B
    size_t xoff = (201216 + (size_t)nnz * 8 + 255) & ~(size_t)255;
    size_t xtsz = (size_t)NB * XROWS * NC * 2;              // 33,423,360 B (xt_h only)
    ushort* xt_h = (ushort*)(wsb + xoff);
    size_t zoff = (xoff + xtsz + 255) & ~(size_t)255;
    ushort* z = (ushort*)(wsb + zoff);
    size_t zavail = (ws_size > zoff) ? ws_size - zoff : 0;

    int CF = 16;
    if      (zavail >= (size_t)128 * 6 * HW * 2) CF = 128;
    else if (zavail >= (size_t)64 * 6 * HW * 2)  CF = 64;
    else if (zavail >= (size_t)32 * 6 * HW * 2)  CF = 32;

    k_transpose_w<<<(NK * NF * NC + 255) / 256, 256, 0, stream>>>(w, wt_h, wt_l);
    k_pack<<<(nnz + 255) / 256, 256, 0, stream>>>(seg, lat, lon, vals, qw, packed, nnz);
    k_bounds<<<(NSEG + 255) / 256, 256, 0, stream>>>(seg, row_start, row_end, nnz);
    k_split<<<dim3((HW + 63) / 64, NB), 256, 0, stream>>>(x, xt_h);

    int hwtiles = (HW + 255) / 256;   // 255
    int mt = (CF < 64) ? CF : 64;
    for (int zf0 = 0; zf0 < NF; zf0 += CF) {
        for (int cf0 = zf0; cf0 < zf0 + CF; cf0 += mt) {
            dim3 gg(hwtiles, NB * NK);
            if (mt == 64)      k_gemm2<64><<<gg, 256, 0, stream>>>(xt_h, wt_h, wt_l, z, cf0, CF, cf0 - zf0);
            else if (mt == 32) k_gemm2<32><<<gg, 256, 0, stream>>>(xt_h, wt_h, wt_l, z, cf0, CF, cf0 - zf0);
            else               k_gemm2<16><<<gg, 256, 0, stream>>>(xt_h, wt_h, wt_l, z, cf0, CF, cf0 - zf0);
        }
        dim3 gs(2 * CF, T_OUT);
        k_sparse<<<gs, 192, 0, stream>>>(z, packed, row_start, row_end, bias, out, zf0, CF);
    }
}